// Round 1
// baseline (956.933 us; speedup 1.0000x reference)
//
#include <hip/hip_runtime.h>
#include <hip/hip_bf16.h>

#define B_ 128
#define S_ 512
#define H_ 1024
#define E_ 1024
#define V_ 50000
#define EXTRA_ 500
#define VE_ 50500
#define EPS_ 1e-8f

typedef __attribute__((ext_vector_type(4))) float f32x4;
typedef __attribute__((ext_vector_type(8))) short bf16x8;

__device__ __forceinline__ unsigned short f2bf(float f) {
    unsigned u = __builtin_bit_cast(unsigned, f);
    u = (u + 0x7FFFu + ((u >> 16) & 1u)) >> 16;
    return (unsigned short)u;
}

__device__ __forceinline__ bf16x8 pack8(const float* f) {
    union { bf16x8 v; unsigned short s[8]; } u;
#pragma unroll
    for (int i = 0; i < 8; ++i) u.s[i] = f2bf(f[i]);
    return u.v;
}

// ---------------- K0: f32 -> bf16 convert (for Wh) ----------------
__global__ __launch_bounds__(256) void cvt_bf16_kernel(const float* __restrict__ in,
                                                       unsigned short* __restrict__ out) {
    int i = (blockIdx.x * 256 + threadIdx.x) * 8;
    float f[8];
    *(float4*)f     = *(const float4*)(in + i);
    *(float4*)(f+4) = *(const float4*)(in + i + 4);
    union { uint4 v; unsigned short s[8]; } u;
#pragma unroll
    for (int j = 0; j < 8; ++j) u.s[j] = f2bf(f[j]);
    *(uint4*)(out + i) = u.v;
}

// ---------------- K1: embedding + layernorm + concat ----------------
__global__ __launch_bounds__(256) void embed_ln_kernel(
    const int* __restrict__ tok, const float* __restrict__ embed,
    const float* __restrict__ g, const float* __restrict__ beta,
    const float* __restrict__ ctx, float* __restrict__ x_cat)
{
    __shared__ float red[256];
    int b = blockIdx.x, t = threadIdx.x;
    const float* row = embed + (size_t)tok[b] * E_;
    float v[4];
    float s = 0.f;
#pragma unroll
    for (int i = 0; i < 4; ++i) { v[i] = row[t + i*256]; s += v[i]; }
    red[t] = s; __syncthreads();
    for (int o = 128; o > 0; o >>= 1) { if (t < o) red[t] += red[t+o]; __syncthreads(); }
    float mu = red[0] * (1.f/E_);
    __syncthreads();
    s = 0.f;
#pragma unroll
    for (int i = 0; i < 4; ++i) { float d = v[i]-mu; s += d*d; }
    red[t] = s; __syncthreads();
    for (int o = 128; o > 0; o >>= 1) { if (t < o) red[t] += red[t+o]; __syncthreads(); }
    float inv = rsqrtf(red[0]*(1.f/E_) + 1e-5f);
    float* xrow = x_cat + (size_t)b * 2048;
#pragma unroll
    for (int i = 0; i < 4; ++i) {
        int j = t + i*256;
        xrow[j] = (v[i]-mu)*inv*g[j] + beta[j];
        xrow[1024 + j] = ctx[b*1024 + j];
    }
}

// ---------------- generic M=128 GEMM: C[128,ldc] = A[128,K] @ W[N,K]^T + bias ----------------
__global__ __launch_bounds__(256) void gemm128_kernel(
    const float* __restrict__ A, const float* __restrict__ W,
    const float* __restrict__ bias, float* __restrict__ C,
    int N, int K, int ldc)
{
    __shared__ char Ab[128*64*2];
    __shared__ char Wb[64*64*2];
    const int t = threadIdx.x;
    const int wid = t >> 6, lane = t & 63;
    const int waveM = wid >> 1, waveN = wid & 1;
    const int lq = lane >> 4, lr = lane & 15;
    const int n0 = blockIdx.x * 64;
    f32x4 acc[4][2] = {};
    for (int kc = 0; kc < K; kc += 64) {
        __syncthreads();
#pragma unroll
        for (int i = 0; i < 4; ++i) {       // stage A chunk [128][64]
            int c = t + i*256;
            int row = c >> 3, k8 = (c & 7) << 3;
            const float* src = A + (size_t)row*K + kc + k8;
            float f[8];
            *(float4*)f     = *(const float4*)src;
            *(float4*)(f+4) = *(const float4*)(src+4);
            int byte = row*128 + ((k8*2) ^ ((row&7)<<4));
            *(bf16x8*)(Ab + byte) = pack8(f);
        }
#pragma unroll
        for (int i = 0; i < 2; ++i) {       // stage W chunk [64][64]
            int c = t + i*256;
            int row = c >> 3, k8 = (c & 7) << 3;
            int n = n0 + row;
            float f[8] = {0,0,0,0,0,0,0,0};
            if (n < N) {
                const float* src = W + (size_t)n*K + kc + k8;
                *(float4*)f     = *(const float4*)src;
                *(float4*)(f+4) = *(const float4*)(src+4);
            }
            int byte = row*128 + ((k8*2) ^ ((row&7)<<4));
            *(bf16x8*)(Wb + byte) = pack8(f);
        }
        __syncthreads();
#pragma unroll
        for (int kf = 0; kf < 2; ++kf) {
            int kk2 = (kf*32 + (lq<<3)) * 2;
            bf16x8 bfr[2];
#pragma unroll
            for (int nf = 0; nf < 2; ++nf) {
                int r = waveN*32 + nf*16 + lr;
                bfr[nf] = *(const bf16x8*)(Wb + r*128 + (kk2 ^ ((r&7)<<4)));
            }
#pragma unroll
            for (int mf = 0; mf < 4; ++mf) {
                int r = waveM*64 + mf*16 + lr;
                bf16x8 afr = *(const bf16x8*)(Ab + r*128 + (kk2 ^ ((r&7)<<4)));
#pragma unroll
                for (int nf = 0; nf < 2; ++nf)
                    acc[mf][nf] = __builtin_amdgcn_mfma_f32_16x16x32_bf16(afr, bfr[nf], acc[mf][nf], 0, 0, 0);
            }
        }
    }
#pragma unroll
    for (int mf = 0; mf < 4; ++mf)
#pragma unroll
        for (int nf = 0; nf < 2; ++nf) {
            int n = n0 + waveN*32 + nf*16 + lr;
            if (n < N) {
                float bv = bias[n];
#pragma unroll
                for (int r = 0; r < 4; ++r) {
                    int m = waveM*64 + mf*16 + (lq<<2) + r;
                    C[(size_t)m*ldc + n] = acc[mf][nf][r] + bv;
                }
            }
        }
}

// ---------------- K4: GRU gates ----------------
__global__ __launch_bounds__(256) void gru_gate_kernel(
    const float* __restrict__ gx, const float* __restrict__ gh,
    const float* __restrict__ h0, float* __restrict__ s_t)
{
    int i = blockIdx.x*256 + threadIdx.x;
    int b = i >> 10, h = i & 1023;
    const float* gxr = gx + (size_t)b*3072;
    const float* ghr = gh + (size_t)b*3072;
    float r = 1.f/(1.f+expf(-(gxr[h]      + ghr[h])));
    float z = 1.f/(1.f+expf(-(gxr[h+1024] + ghr[h+1024])));
    float n = tanhf(gxr[h+2048] + r*ghr[h+2048]);
    s_t[i] = (1.f-z)*n + z*h0[i];
}

// ---------------- K6: fused e_t = Vv . tanh(enc@Wh^T + dec_feat + cov*Wc) ----------------
__global__ __launch_bounds__(512) void attn_et_kernel(
    const float* __restrict__ enc,        // [B,S,H] f32
    const unsigned short* __restrict__ whb, // [H,H] bf16 (n,k)
    const float* __restrict__ dec_feat,   // [B,H]
    const float* __restrict__ coverage,   // [B,S]
    const float* __restrict__ Wc,         // [H]
    const float* __restrict__ Vv,         // [H]
    float* __restrict__ e_t)              // [B*S]
{
    extern __shared__ char sm[];
    char* Ab = sm;                           // 64*1024*2 = 131072 B
    char* Wb = sm + 131072;                  // 128*64*2  = 16384 B
    float* e_lds = (float*)(sm + 147456);    // 64 f32
    const int t = threadIdx.x;
    const int wid = t >> 6, lane = t & 63;
    const int waveM = wid >> 2, waveN = wid & 3;
    const int lq = lane >> 4, lr = lane & 15;
    const int m0 = blockIdx.x * 64;
    const int b = m0 >> 9;
    const int s0 = m0 & 511;

    // stage A tile [64 rows][1024 k] f32->bf16, swizzled
#pragma unroll
    for (int i = 0; i < 16; ++i) {
        int c = t + i*512;
        int row = c >> 7, k8 = (c & 127) << 3;
        const float* src = enc + (size_t)(m0+row)*H_ + k8;
        float f[8];
        *(float4*)f     = *(const float4*)src;
        *(float4*)(f+4) = *(const float4*)(src+4);
        int byte = row*2048 + ((k8*2) ^ ((row&7)<<4));
        *(bf16x8*)(Ab + byte) = pack8(f);
    }
    if (t < 64) e_lds[t] = 0.f;

    float cov[2][4];
#pragma unroll
    for (int mf = 0; mf < 2; ++mf)
#pragma unroll
        for (int r = 0; r < 4; ++r)
            cov[mf][r] = coverage[b*S_ + s0 + waveM*32 + mf*16 + (lq<<2) + r];
    __syncthreads();

    float e_acc[2][4] = {};
    const f32x4 z4 = {0.f,0.f,0.f,0.f};
    for (int nc = 0; nc < 1024; nc += 128) {
        f32x4 acc[2][2];
#pragma unroll
        for (int mf = 0; mf < 2; ++mf)
#pragma unroll
            for (int nf = 0; nf < 2; ++nf) acc[mf][nf] = z4;

        for (int kc = 0; kc < 1024; kc += 64) {
            __syncthreads();
#pragma unroll
            for (int i = 0; i < 2; ++i) {    // stage W chunk [128][64] bf16
                int c = t + i*512;
                int nl = c >> 3, k8 = (c & 7) << 3;
                uint4 v = *(const uint4*)(whb + (size_t)(nc+nl)*H_ + kc + k8);
                int byte = nl*128 + ((k8*2) ^ ((nl&7)<<4));
                *(uint4*)(Wb + byte) = v;
            }
            __syncthreads();
#pragma unroll
            for (int kf = 0; kf < 2; ++kf) {
                int kkl = kf*32 + (lq<<3);
                bf16x8 bfr[2];
#pragma unroll
                for (int nf = 0; nf < 2; ++nf) {
                    int r = waveN*32 + nf*16 + lr;
                    bfr[nf] = *(const bf16x8*)(Wb + r*128 + ((kkl*2) ^ ((r&7)<<4)));
                }
#pragma unroll
                for (int mf = 0; mf < 2; ++mf) {
                    int r = waveM*32 + mf*16 + lr;
                    bf16x8 afr = *(const bf16x8*)(Ab + r*2048 + (((kc+kkl)*2) ^ ((r&7)<<4)));
#pragma unroll
                    for (int nf = 0; nf < 2; ++nf)
                        acc[mf][nf] = __builtin_amdgcn_mfma_f32_16x16x32_bf16(afr, bfr[nf], acc[mf][nf], 0, 0, 0);
                }
            }
        }
        // epilogue: tanh + Vv reduce for this 128-col chunk
#pragma unroll
        for (int mf = 0; mf < 2; ++mf)
#pragma unroll
            for (int nf = 0; nf < 2; ++nf) {
                int ng = nc + waveN*32 + nf*16 + lr;
                float df = dec_feat[b*H_ + ng];
                float wc = Wc[ng];
                float vv = Vv[ng];
#pragma unroll
                for (int r = 0; r < 4; ++r)
                    e_acc[mf][r] += tanhf(acc[mf][nf][r] + df + cov[mf][r]*wc) * vv;
            }
    }
    // butterfly over lane&15 (sum over the 16 columns held per lane group)
#pragma unroll
    for (int msk = 1; msk < 16; msk <<= 1)
#pragma unroll
        for (int mf = 0; mf < 2; ++mf)
#pragma unroll
            for (int r = 0; r < 4; ++r)
                e_acc[mf][r] += __shfl_xor(e_acc[mf][r], msk);
    if (lr == 0) {
#pragma unroll
        for (int mf = 0; mf < 2; ++mf)
#pragma unroll
            for (int r = 0; r < 4; ++r)
                atomicAdd(&e_lds[waveM*32 + mf*16 + (lq<<2) + r], e_acc[mf][r]);
    }
    __syncthreads();
    if (t < 64) e_t[m0 + t] = e_lds[t];
}

// ---------------- K7: softmax over S + coverage ----------------
__global__ __launch_bounds__(256) void attn_softmax_kernel(
    const float* __restrict__ e_t, const float* __restrict__ mask,
    const float* __restrict__ cov, float* __restrict__ att,
    float* __restrict__ cov_next, float* __restrict__ loss)
{
    __shared__ float red[256];
    int b = blockIdx.x, t = threadIdx.x;
    int i1 = b*S_ + t, i2 = i1 + 256;
    float e1 = e_t[i1] + mask[i1];
    float e2 = e_t[i2] + mask[i2];
    red[t] = fmaxf(e1, e2); __syncthreads();
    for (int o = 128; o > 0; o >>= 1) { if (t < o) red[t] = fmaxf(red[t], red[t+o]); __syncthreads(); }
    float m = red[0]; __syncthreads();
    float a1 = expf(e1-m), a2 = expf(e2-m);
    red[t] = a1+a2; __syncthreads();
    for (int o = 128; o > 0; o >>= 1) { if (t < o) red[t] += red[t+o]; __syncthreads(); }
    float inv = 1.f/red[0]; __syncthreads();
    a1 *= inv; a2 *= inv;
    att[i1] = a1; att[i2] = a2;
    float c1 = cov[i1]+a1, c2 = cov[i2]+a2;
    cov_next[i1] = c1; cov_next[i2] = c2;
    red[t] = fminf(a1,c1)+fminf(a2,c2); __syncthreads();
    for (int o = 128; o > 0; o >>= 1) { if (t < o) red[t] += red[t+o]; __syncthreads(); }
    if (t == 0) loss[b] = red[0];
}

// ---------------- K8: h_t = att @ enc ----------------
__global__ __launch_bounds__(256) void context_kernel(
    const float* __restrict__ att, const float* __restrict__ enc, float* __restrict__ h_t)
{
    __shared__ float asl[512];
    __shared__ float part[4][64];
    int b = blockIdx.x, hc = blockIdx.y;
    int t = threadIdx.x;
    asl[t] = att[b*S_ + t];
    asl[t+256] = att[b*S_ + t + 256];
    __syncthreads();
    int h = hc*64 + (t & 63);
    int sq = t >> 6;
    const float* ep = enc + (size_t)b*S_*H_ + (size_t)sq*128*H_ + h;
    float acc = 0.f;
#pragma unroll 4
    for (int s = 0; s < 128; ++s)
        acc += asl[sq*128 + s] * ep[(size_t)s*H_];
    part[sq][t & 63] = acc;
    __syncthreads();
    if (t < 64) h_t[(size_t)b*H_ + hc*64 + t] = part[0][t]+part[1][t]+part[2][t]+part[3][t];
}

// ---------------- K9: p_gen + build A2=[s_t,h_t] ----------------
__global__ __launch_bounds__(256) void pgen_kernel(
    const float* __restrict__ h_t, const float* __restrict__ s_t, const float* __restrict__ x,
    const float* __restrict__ pgW, const float* __restrict__ pgb,
    float* __restrict__ pgen, float* __restrict__ A2)
{
    __shared__ float red[256];
    int b = blockIdx.x, t = threadIdx.x;
    float s = 0.f;
#pragma unroll
    for (int i = 0; i < 12; ++i) {
        int j = t + i*256;
        float v = (j < 1024) ? h_t[b*1024+j] : (j < 2048 ? s_t[b*1024 + j-1024] : x[b*1024 + j-2048]);
        s += v * pgW[j];
    }
    red[t] = s; __syncthreads();
    for (int o = 128; o > 0; o >>= 1) { if (t < o) red[t] += red[t+o]; __syncthreads(); }
    if (t == 0) {
        float p = 1.f/(1.f+expf(-(red[0] + pgb[0])));
        pgen[b] = fmaxf(p, EPS_);
    }
#pragma unroll
    for (int i = 0; i < 8; ++i) {
        int j = t + i*256;
        A2[(size_t)b*2048 + j] = (j < 1024) ? s_t[b*1024+j] : h_t[b*1024+j-1024];
    }
}

// ---------------- K12: vocab softmax in place (out0 holds logits) ----------------
__global__ __launch_bounds__(1024) void vocab_softmax_kernel(
    float* __restrict__ out0, const float* __restrict__ pgen)
{
    __shared__ float rm[1024], rl[1024];
    int b = blockIdx.x, t = threadIdx.x;
    float* row = out0 + (size_t)b*VE_;
    float m = -1e30f, l = 0.f;
    for (int i = t; i < V_; i += 1024) {
        float xv = row[i];
        if (xv > m) { l = l*__expf(m-xv) + 1.f; m = xv; }
        else l += __expf(xv-m);
    }
    rm[t] = m; rl[t] = l; __syncthreads();
    for (int o = 512; o > 0; o >>= 1) {
        if (t < o) {
            float m1 = rm[t], m2 = rm[t+o];
            float M = fmaxf(m1, m2);
            rl[t] = rl[t]*__expf(m1-M) + rl[t+o]*__expf(m2-M);
            rm[t] = M;
        }
        __syncthreads();
    }
    float M = rm[0], inv = pgen[b]/rl[0];
    for (int i = t; i < V_; i += 1024)
        row[i] = __expf(row[i]-M)*inv;
    for (int i = V_ + t; i < VE_; i += 1024)
        row[i] = 0.f;
}

// ---------------- K13: scatter-add copy distribution ----------------
__global__ __launch_bounds__(256) void scatter_kernel(
    const int* __restrict__ ebev, const float* __restrict__ att,
    const float* __restrict__ pgen, float* __restrict__ out0)
{
    int i = blockIdx.x*256 + threadIdx.x;   // < B*S
    int b = i >> 9;
    float val = (1.f - pgen[b]) * att[i];
    int col = ebev[i];
    atomicAdd(out0 + (size_t)b*VE_ + col, val);
}

// ---------------- K14: clip + log in place ----------------
__global__ __launch_bounds__(256) void log_kernel(float* __restrict__ out0)
{
    int i = (blockIdx.x*256 + threadIdx.x) * 4;
    if (i >= B_*VE_) return;
    float4 v = *(float4*)(out0 + i);
    v.x = logf(fmaxf(v.x, EPS_));
    v.y = logf(fmaxf(v.y, EPS_));
    v.z = logf(fmaxf(v.z, EPS_));
    v.w = logf(fmaxf(v.w, EPS_));
    *(float4*)(out0 + i) = v;
}

extern "C" void kernel_launch(void* const* d_in, const int* in_sizes, int n_in,
                              void* d_out, int out_size, void* d_ws, size_t ws_size,
                              hipStream_t stream) {
    const int*   tok        = (const int*)d_in[0];
    const float* dec_hidden = (const float*)d_in[1];
    const float* enc        = (const float*)d_in[2];
    const float* mask       = (const float*)d_in[3];
    const float* ctx1       = (const float*)d_in[4];
    const int*   ebev       = (const int*)d_in[5];
    const float* cov        = (const float*)d_in[7];
    const float* embed      = (const float*)d_in[8];
    const float* ln_g       = (const float*)d_in[9];
    const float* ln_b       = (const float*)d_in[10];
    const float* xc_W       = (const float*)d_in[11];
    const float* xc_b       = (const float*)d_in[12];
    const float* W_ih       = (const float*)d_in[13];
    const float* W_hh       = (const float*)d_in[14];
    const float* b_ih       = (const float*)d_in[15];
    const float* b_hh       = (const float*)d_in[16];
    const float* Wh         = (const float*)d_in[17];
    const float* Ws         = (const float*)d_in[18];
    const float* Ws_b       = (const float*)d_in[19];
    const float* Wc         = (const float*)d_in[20];
    const float* Vv         = (const float*)d_in[21];
    const float* pg_W       = (const float*)d_in[22];
    const float* pg_b       = (const float*)d_in[23];
    const float* out1_W     = (const float*)d_in[24];
    const float* out1_b     = (const float*)d_in[25];
    const float* out2_W     = (const float*)d_in[26];
    const float* out2_b     = (const float*)d_in[27];

    float* out      = (float*)d_out;
    float* s_t      = out + 6464000;   // [B,H]
    float* h_t      = out + 6595072;   // [B,H]
    float* cov_next = out + 6726144;   // [B,S]
    float* loss     = out + 6791680;   // [B]

    float* wsf = (float*)d_ws;
    unsigned short* whb = (unsigned short*)d_ws;   // 1M bf16 -> 524288 f32 slots
    float* x_cat    = wsf + 524288;    // [B,2048]
    float* x        = wsf + 786432;    // [B,1024]
    float* gx       = wsf + 917504;    // [B,3072]
    float* gh       = wsf + 1310720;   // [B,3072]
    float* dec_feat = wsf + 1703936;   // [B,1024]
    float* e_t      = wsf + 1835008;   // [B,S]
    float* att      = wsf + 1900544;   // [B,S]
    float* pgen     = wsf + 1966080;   // [B]
    float* A2       = wsf + 1966208;   // [B,2048]
    float* h2       = wsf + 2228352;   // [B,1024]

    // K0: Wh -> bf16
    cvt_bf16_kernel<<<512, 256, 0, stream>>>(Wh, whb);
    // K1: embedding + LN + concat context
    embed_ln_kernel<<<128, 256, 0, stream>>>(tok, embed, ln_g, ln_b, ctx1, x_cat);
    // K2: x = x_cat @ xc_W^T + xc_b
    gemm128_kernel<<<16, 256, 0, stream>>>(x_cat, xc_W, xc_b, x, 1024, 2048, 1024);
    // K3: GRU gate GEMMs
    gemm128_kernel<<<48, 256, 0, stream>>>(x, W_ih, b_ih, gx, 3072, 1024, 3072);
    gemm128_kernel<<<48, 256, 0, stream>>>(dec_hidden, W_hh, b_hh, gh, 3072, 1024, 3072);
    // K4: gates -> s_t (written directly to output region)
    gru_gate_kernel<<<512, 256, 0, stream>>>(gx, gh, dec_hidden, s_t);
    // K5: dec_feat = s_t @ Ws^T + Ws_b
    gemm128_kernel<<<16, 256, 0, stream>>>(s_t, Ws, Ws_b, dec_feat, 1024, 1024, 1024);
    // K6: fused attention scores
    attn_et_kernel<<<1024, 512, 147712, stream>>>(enc, whb, dec_feat, cov, Wc, Vv, e_t);
    // K7: softmax over S, coverage_next, coverage_loss
    attn_softmax_kernel<<<128, 256, 0, stream>>>(e_t, mask, cov, att, cov_next, loss);
    // K8: h_t = att @ enc
    dim3 g8(128, 16);
    context_kernel<<<g8, 256, 0, stream>>>(att, enc, h_t);
    // K9: p_gen + A2
    pgen_kernel<<<128, 256, 0, stream>>>(h_t, s_t, x, pg_W, pg_b, pgen, A2);
    // K10: h2 = A2 @ out1_W^T + out1_b
    gemm128_kernel<<<16, 256, 0, stream>>>(A2, out1_W, out1_b, h2, 1024, 2048, 1024);
    // K11: logits = h2 @ out2_W^T + out2_b   (straight into out0, ldc=50500)
    gemm128_kernel<<<782, 256, 0, stream>>>(h2, out2_W, out2_b, out, 50000, 1024, 50500);
    // K12: vocab softmax in place, scale by p_gen, zero EXTRA cols
    vocab_softmax_kernel<<<128, 1024, 0, stream>>>(out, pgen);
    // K13: scatter-add copy distribution
    scatter_kernel<<<256, 256, 0, stream>>>(ebev, att, pgen, out);
    // K14: clip + log
    log_kernel<<<6313, 256, 0, stream>>>(out);
}